// Round 11
// baseline (25.522 us; speedup 1.0000x reference)
//
#include <hip/hip_runtime.h>
#include <hip/hip_fp16.h>

// Kuramoto closed-loop — prep + MFMA main.
//
//  The 6 row-sums are ONE matrix product: S = A(4096x4096, 0/1) @ T(4096x6),
//  T types: {c, s, c*x2, s*x2, v, x2}. mfma_f32_16x16x32_f16 accumulates the
//  k-reduction in the matrix pipe -> no shuffle butterfly, no fdot chain.
//  deg (gamma Rayleigh sample) via fdot2(a, 1) per lane, exact in f32.
//
// Lessons ledger:
//  r1/r3/r4: register tables spill -> WRITE_SIZE is the spill alarm.
//  r5:  prefetch distance must match buffer count.
//  r6:  split-array LDS layout for conflict-free b128.
//  r7:  builtins use __fp16 vectors on this toolchain (decltype/explicit).
//  r8:  redundant per-block table build dominated VALU -> prep kernel.
//  r9/r10: 22-23us plateau. Steady-state FETCH=65KB (adj L3-resident) yet no
//       speedup -> NOT BW-bound; DS pipe (32 b128 + 42 shfl per row-wave) and
//       VALU issue are the wall. -> r11: MFMA does the reduction.
//
// k_main: 256 blocks x 1024 thr. Block = 16 rows; wave w covers k in
// [w*256, w*256+256), 8 k-steps of 32. LDS table type-major, stride 4104
// halfwords (8208 B: bank shift 4/type -> b128 reads at the 4-phase minimum).
// A-frag: lane holds A[row=lane&15][k=kbase+(lane>>4)*8+0..7] (f32->f16 RTZ,
// exact for 0/1). B-frag: tab[type=(lane&15)%6][same k] (cols 6..15 are dup
// garbage, never read). D (m89-verified): col=lane&15, row=(lane>>4)*4+reg.

#define NN 4096
#define KCOUPLING 3.0f
#define TSTRIDE 4104  // halfwords per type row in LDS (8208 B)

typedef decltype(__builtin_amdgcn_cvt_pkrtz(0.0f, 0.0f)) h2_t;  // __fp16 x2
typedef __fp16 f16x8 __attribute__((ext_vector_type(8)));
typedef float f32x4 __attribute__((ext_vector_type(4)));

__device__ __forceinline__ h2_t pkrtz(float a, float b) {
  return __builtin_amdgcn_cvt_pkrtz(a, b);  // RTZ: exact for 0/1
}
__device__ __forceinline__ unsigned pk2rn_u(float a, float b) {  // RN for table
  __half2 h = __floats2half2_rn(a, b);
  return *reinterpret_cast<unsigned*>(&h);
}
__device__ __forceinline__ float fdot2(h2_t a, h2_t b, float c) {
#if __has_builtin(__builtin_amdgcn_fdot2)
  return __builtin_amdgcn_fdot2(a, b, c, false);
#else
  return fmaf((float)a.x, (float)b.x, fmaf((float)a.y, (float)b.y, c));
#endif
}

// ---- prep: packed type-major f16 table, built once. thread g -> cols 4g..4g+3
__global__ __launch_bounds__(64) void k_prep(
    const float* __restrict__ x, const float* __restrict__ K,
    const float* __restrict__ b, const float* __restrict__ G,
    __fp16* __restrict__ tabG, float2* __restrict__ aux) {
  const int g = blockIdx.x * 64 + threadIdx.x;  // 0..1023
  const int j0 = 4 * g;
  const float4 x1v = *(const float4*)(x + j0);
  const float4 x2v = *(const float4*)(x + NN + j0);
  const float4 xiA = *(const float4*)(x + 2 * NN + 2 * j0);
  const float4 xiB = *(const float4*)(x + 2 * NN + 2 * j0 + 4);
  const float4 bv0 = *(const float4*)(b + 2 * j0);
  const float4 bv1 = *(const float4*)(b + 2 * j0 + 4);
  const float4 gv0 = *(const float4*)(G + 2 * j0);
  const float4 gv1 = *(const float4*)(G + 2 * j0 + 4);
  const float x1s[4] = {x1v.x, x1v.y, x1v.z, x1v.w};
  const float x2s[4] = {x2v.x, x2v.y, x2v.z, x2v.w};
  const float xis[8] = {xiA.x, xiA.y, xiA.z, xiA.w,
                        xiB.x, xiB.y, xiB.z, xiB.w};
  const float bs[8]  = {bv0.x, bv0.y, bv0.z, bv0.w,
                        bv1.x, bv1.y, bv1.z, bv1.w};
  const float gs[8]  = {gv0.x, gv0.y, gv0.z, gv0.w,
                        gv1.x, gv1.y, gv1.z, gv1.w};
  float cf[4], sf[4], vf[4], cx[4], sx[4];
#pragma unroll
  for (int c = 0; c < 4; ++c) {
    const float4 Kv = *(const float4*)(K + 4 * (j0 + c));
    const float M0 = tanhf(fmaf(Kv.x, xis[2 * c], fmaf(Kv.y, xis[2 * c + 1], bs[2 * c])));
    const float M1 = tanhf(fmaf(Kv.z, xis[2 * c], fmaf(Kv.w, xis[2 * c + 1], bs[2 * c + 1])));
    const float d0 = Kv.x * M0 + Kv.z * M1;
    const float d1 = Kv.y * M0 + Kv.w * M1;
    vf[c] = gs[2 * c] * d0 + gs[2 * c + 1] * d1;
    cf[c] = cosf(x1s[c]);
    sf[c] = sinf(x1s[c]);
    cx[c] = cf[c] * x2s[c];
    sx[c] = sf[c] * x2s[c];
    aux[j0 + c] = make_float2(d0, d1);
  }
  uint2* tg = (uint2*)tabG;  // type T row = 1024 uint2
  tg[0 * 1024 + g] = make_uint2(pk2rn_u(cf[0], cf[1]), pk2rn_u(cf[2], cf[3]));
  tg[1 * 1024 + g] = make_uint2(pk2rn_u(sf[0], sf[1]), pk2rn_u(sf[2], sf[3]));
  tg[2 * 1024 + g] = make_uint2(pk2rn_u(cx[0], cx[1]), pk2rn_u(cx[2], cx[3]));
  tg[3 * 1024 + g] = make_uint2(pk2rn_u(sx[0], sx[1]), pk2rn_u(sx[2], sx[3]));
  tg[4 * 1024 + g] = make_uint2(pk2rn_u(vf[0], vf[1]), pk2rn_u(vf[2], vf[3]));
  tg[5 * 1024 + g] = make_uint2(pk2rn_u(x2s[0], x2s[1]), pk2rn_u(x2s[2], x2s[3]));
}

// ---- main: 16 rows/block, 16 waves split K, MFMA accumulate ----
__global__ __launch_bounds__(1024, 4) void k_main(
    const float* __restrict__ x, const float* __restrict__ adj,
    const float* __restrict__ G, const __fp16* __restrict__ tabG,
    const float2* __restrict__ aux, float* __restrict__ out) {
  const int t = threadIdx.x;
  const int lane = t & 63, w = t >> 6;  // wave 0..15
  const int r0 = blockIdx.x * 16;

  __shared__ __align__(16) char smem[6 * TSTRIDE * 2];  // 49248 B
  __fp16* tab = (__fp16*)smem;                 // [6][TSTRIDE] during k-loop
  float* red  = (float*)smem;                  // [16][64][4] after (16384 B)
  float* red2 = (float*)(smem + 16384);        // [16][16] deg partials
  float* ds2  = (float*)(smem + 17408);        // [64][4] reduced D
  float* gdeg = (float*)(smem + 18432);        // [16]

  const int mrow = lane & 15;          // A-frag row within tile
  const int kgrp = lane >> 4;          // k-chunk group 0..3
  const int tt = (lane & 15) % 6;      // B-frag type (cols >=6 dup, unread)
  const float* arow = adj + (size_t)(r0 + mrow) * NN;
  const int kb0 = w * 256 + kgrp * 8;

  // issue first 4 k-steps' A loads; table copy hides their latency
  float4 A0[4], A1[4];
#pragma unroll
  for (int s = 0; s < 4; ++s) {
    A0[s] = *(const float4*)(arow + kb0 + s * 32);
    A1[s] = *(const float4*)(arow + kb0 + s * 32 + 4);
  }

  // global packed [6][4096] f16 -> LDS padded [6][TSTRIDE]
#pragma unroll
  for (int T = 0; T < 6; ++T) {
    uint2 v = ((const uint2*)tabG)[T * 1024 + t];
    *(uint2*)(tab + T * TSTRIDE + t * 4) = v;
  }
  __syncthreads();

  f32x4 acc = {0.f, 0.f, 0.f, 0.f};
  float deg = 0.f;
  const h2_t one2 = pkrtz(1.0f, 1.0f);
  const __fp16* bbase = tab + tt * TSTRIDE + kgrp * 8;

#pragma unroll
  for (int s = 0; s < 8; ++s) {
    const float4 a0 = A0[s & 3], a1 = A1[s & 3];
    if (s + 4 < 8) {
      A0[s & 3] = *(const float4*)(arow + kb0 + (s + 4) * 32);
      A1[s & 3] = *(const float4*)(arow + kb0 + (s + 4) * 32 + 4);
    }
    union { h2_t h[4]; f16x8 v; } af;
    af.h[0] = pkrtz(a0.x, a0.y);
    af.h[1] = pkrtz(a0.z, a0.w);
    af.h[2] = pkrtz(a1.x, a1.y);
    af.h[3] = pkrtz(a1.z, a1.w);
    deg = fdot2(af.h[0], one2, deg);
    deg = fdot2(af.h[1], one2, deg);
    deg = fdot2(af.h[2], one2, deg);
    deg = fdot2(af.h[3], one2, deg);
    const f16x8 bf = *(const f16x8*)(bbase + w * 256 + s * 32);
    acc = __builtin_amdgcn_mfma_f32_16x16x32_f16(af.v, bf, acc, 0, 0, 0);
  }

  // deg: sum the 4 k-groups per row -> lanes 0..15 hold rows 0..15
  deg += __shfl_xor(deg, 16);
  deg += __shfl_xor(deg, 32);

  __syncthreads();  // all waves done reading tab; safe to overlay
  *(f32x4*)(red + (w * 64 + lane) * 4) = acc;
  if (lane < 16) red2[w * 16 + lane] = deg;
  __syncthreads();

  // element-wise sum of 16 wave-partials: 256 threads, 1 element each
  if (t < 256) {
    const int le = t >> 2, rg = t & 3;
    float s = 0.f;
#pragma unroll
    for (int ww = 0; ww < 16; ++ww) s += red[(ww * 64 + le) * 4 + rg];
    ds2[t] = s;  // ds2[le*4+rg]
  }
  __syncthreads();

  // finalize: thread r owns block-row r. D[r][n] at lane ((r>>2)<<4)|n, reg r&3
  if (t < 16) {
    const int r = t, i = r0 + r;
    float S[6];
#pragma unroll
    for (int n = 0; n < 6; ++n) S[n] = ds2[(((r >> 2) << 4) | n) * 4 + (r & 3)];
    float degr = 0.f;
#pragma unroll
    for (int ww = 0; ww < 16; ++ww) degr += red2[ww * 16 + r];

    const float x1i = x[i];
    const float x2i = x[NN + i];
    const float ci = cosf(x1i), si = sinf(x1i);
    const float sint = ci * x2i * S[0] + si * x2i * S[1] - ci * S[2] - si * S[3];
    out[i] = x2i;
    out[NN + i] = (KCOUPLING / (float)NN) * (-S[4]) * sint;

    const float G0 = G[2 * i], G1 = G[2 * i + 1];
    const float sw = (G0 * G0 + G1 * G1) * (1.0f / ((float)NN * (float)NN));
    gdeg[r] = sw * degr * degr;
    ds2[r] = S[5];  // stash Ax2 for after the sync (ds2[0..15] free to reuse)
    red2[r] = G0;   // stash (regions no longer needed)
    red2[16 + r] = G1;
  }
  __syncthreads();
  if (t < 16) {
    const int r = t, i = r0 + r;
    float gp = 0.f;
#pragma unroll
    for (int q = 0; q < 16; ++q) gp += gdeg[q];
    const float gamma = 0.85f * gp * (1.0f / 16.0f);
    const float2 au = aux[i];
    const float Rx2 = ds2[r];
    const float G0 = red2[r], G1 = red2[16 + r];
    out[2 * NN + 2 * i + 0] = -au.y - gamma * au.x + (G0 * (1.0f / NN)) * Rx2;
    out[2 * NN + 2 * i + 1] =  au.x - gamma * au.y + (G1 * (1.0f / NN)) * Rx2;
  }
}

extern "C" void kernel_launch(void* const* d_in, const int* in_sizes, int n_in,
                              void* d_out, int out_size, void* d_ws,
                              size_t ws_size, hipStream_t stream) {
  (void)in_sizes; (void)n_in; (void)out_size; (void)ws_size;
  const float* x   = (const float*)d_in[1];
  const float* adj = (const float*)d_in[2];
  const float* K   = (const float*)d_in[3];
  const float* b   = (const float*)d_in[4];
  const float* G   = (const float*)d_in[5];
  float* out = (float*)d_out;

  char* ws = (char*)d_ws;
  __fp16* tabG = (__fp16*)ws;              // 6*4096*2 = 49152 B
  float2* aux  = (float2*)(ws + 49152);    // 32768 B

  k_prep<<<16, 64, 0, stream>>>(x, K, b, G, tabG, aux);
  k_main<<<256, 1024, 0, stream>>>(x, adj, G, tabG, aux, out);
}

// Round 12
// 20.468 us; speedup vs baseline: 1.2469x; 1.2469x over previous
//
#include <hip/hip_runtime.h>
#include <hip/hip_fp16.h>

// Kuramoto closed-loop — prep + main.
//
//  s_int[j] = cj*x2j*(A c)j + sj*x2j*(A s)j - cj*(A (c*x2))j - sj*(A (s*x2))j
//  u        = -(A v),  v_i = G0*dH2_0 + G1*dH2_1
//  gterm    = G2d/n * (A x2)
//  gamma   ~= 0.85 * mean_{rows of block}(sw_i * deg_i^2)  (Rayleigh sample)
//
// Lessons ledger:
//  r1/r3/r4: register tables spill -> WRITE_SIZE is the spill alarm.
//  r5:  prefetch distance must match buffer count.
//  r6:  split tabE/tabO arrays -> conflict-free b128 (655K -> 0).
//  r7:  builtins return __fp16 vectors -> decltype the builtin.
//  r8:  redundant per-block table build dominated VALU -> prep kernel.
//  r9:  PASS 22.1 (best). r10 (16-f4 MLP): 23.1. r11 (MFMA): 25.5.
//  r9-r11 meta: three different compute engines, same 22-25us -> the wall is
//       the 64MB zero-reuse adjacency stream (~3-4 TB/s effective vs 6.7 the
//       fill sustains). Hypothesis: per-CU miss-latency cap + L2 thrash.
//  r12(this): nontemporal adjacency loads (L2 no-allocate; table/x/aux keep
//       normal caching), r9 structure, two-half schedule (8 f4 in flight,
//       VGPR ~100 < 128 cap).

#define NN 4096
#define KCOUPLING 3.0f
#define ROWS 8
#define NBLK (NN / ROWS)  // 512 blocks x 512 thr

typedef decltype(__builtin_amdgcn_cvt_pkrtz(0.0f, 0.0f)) h2_t;  // __fp16 x2
typedef float f4_t __attribute__((ext_vector_type(4)));

__device__ __forceinline__ h2_t pk2(float a, float b) {  // RTZ: 0/1 exact
  return __builtin_amdgcn_cvt_pkrtz(a, b);
}
__device__ __forceinline__ unsigned pk2rn_u(float a, float b) {  // RN table
  __half2 h = __floats2half2_rn(a, b);
  return *reinterpret_cast<unsigned*>(&h);
}
__device__ __forceinline__ float fdot2(h2_t a, h2_t b, float c) {
#if __has_builtin(__builtin_amdgcn_fdot2)
  return __builtin_amdgcn_fdot2(a, b, c, false);
#else
  return fmaf((float)a.x, (float)b.x, fmaf((float)a.y, (float)b.y, c));
#endif
}
__device__ __forceinline__ h2_t bch2(unsigned u) {
  union { unsigned u; h2_t h; } x; x.u = u; return x.h;
}
__device__ __forceinline__ f4_t ntload4(const f4_t* p) {
  return __builtin_nontemporal_load(p);
}

// ---- prep: build packed col table ONCE. thread g -> cols 4g..4g+3 ----
__global__ __launch_bounds__(64) void k_prep(
    const float* __restrict__ x, const float* __restrict__ K,
    const float* __restrict__ b, const float* __restrict__ G,
    uint4* __restrict__ wsE, uint4* __restrict__ wsO,
    float2* __restrict__ aux) {
  const int g = blockIdx.x * 64 + threadIdx.x;  // 0..1023
  const int j0 = 4 * g;
  const float4 x1v = *(const float4*)(x + j0);
  const float4 x2v = *(const float4*)(x + NN + j0);
  const float4 xiA = *(const float4*)(x + 2 * NN + 2 * j0);
  const float4 xiB = *(const float4*)(x + 2 * NN + 2 * j0 + 4);
  const float4 bv0 = *(const float4*)(b + 2 * j0);
  const float4 bv1 = *(const float4*)(b + 2 * j0 + 4);
  const float4 gv0 = *(const float4*)(G + 2 * j0);
  const float4 gv1 = *(const float4*)(G + 2 * j0 + 4);
  const float x1s[4] = {x1v.x, x1v.y, x1v.z, x1v.w};
  const float x2s[4] = {x2v.x, x2v.y, x2v.z, x2v.w};
  const float xis[8] = {xiA.x, xiA.y, xiA.z, xiA.w,
                        xiB.x, xiB.y, xiB.z, xiB.w};
  const float bs[8]  = {bv0.x, bv0.y, bv0.z, bv0.w,
                        bv1.x, bv1.y, bv1.z, bv1.w};
  const float gs[8]  = {gv0.x, gv0.y, gv0.z, gv0.w,
                        gv1.x, gv1.y, gv1.z, gv1.w};
  float cf[4], sf[4], vf[4];
#pragma unroll
  for (int c = 0; c < 4; ++c) {
    const float4 Kv = *(const float4*)(K + 4 * (j0 + c));
    const float M0 = tanhf(fmaf(Kv.x, xis[2 * c], fmaf(Kv.y, xis[2 * c + 1], bs[2 * c])));
    const float M1 = tanhf(fmaf(Kv.z, xis[2 * c], fmaf(Kv.w, xis[2 * c + 1], bs[2 * c + 1])));
    const float d0 = Kv.x * M0 + Kv.z * M1;
    const float d1 = Kv.y * M0 + Kv.w * M1;
    vf[c] = gs[2 * c] * d0 + gs[2 * c + 1] * d1;
    cf[c] = cosf(x1s[c]);
    sf[c] = sinf(x1s[c]);
    aux[j0 + c] = make_float2(d0, d1);
  }
  wsE[g] = make_uint4(pk2rn_u(cf[0], cf[1]), pk2rn_u(sf[0], sf[1]),
                      pk2rn_u(x2s[0], x2s[1]), pk2rn_u(vf[0], vf[1]));
  wsO[g] = make_uint4(pk2rn_u(cf[2], cf[3]), pk2rn_u(sf[2], sf[3]),
                      pk2rn_u(x2s[2], x2s[3]), pk2rn_u(vf[2], vf[3]));
}

// ---- main: wave-per-row; nontemporal adjacency; two-half schedule ----
__global__ __launch_bounds__(512, 4) void k_main(
    const float* __restrict__ x, const f4_t* __restrict__ adj4,
    const float* __restrict__ G, const uint4* __restrict__ wsE,
    const uint4* __restrict__ wsO, const float2* __restrict__ aux,
    float* __restrict__ out) {
  const int t = threadIdx.x;
  const int lane = t & 63, w = t >> 6;
  const int row = blockIdx.x * ROWS + w;

  __shared__ uint4 tabE[NN / 4];  // 16 KB
  __shared__ uint4 tabO[NN / 4];  // 16 KB
  __shared__ float gdeg[ROWS];

  const int base = row * 1024 + lane;  // f4 units; row stride 1024 f4

  // half 0 in flight before table staging
  f4_t A[8], B[8];
#pragma unroll
  for (int j = 0; j < 8; ++j) A[j] = ntload4(adj4 + base + j * 64);

  tabE[t] = wsE[t];
  tabE[t + 512] = wsE[t + 512];
  tabO[t] = wsO[t];
  tabO[t + 512] = wsO[t + 512];
  __syncthreads();

  // half 1 in flight while half 0 computes
#pragma unroll
  for (int j = 0; j < 8; ++j) B[j] = ntload4(adj4 + base + (8 + j) * 64);

  float a0 = 0.f, a1 = 0.f, a2 = 0.f, a3 = 0.f, a4 = 0.f, a5 = 0.f, a6 = 0.f;
  const h2_t ONE = bch2(pk2rn_u(1.0f, 1.0f));

#pragma unroll
  for (int half = 0; half < 2; ++half) {
#pragma unroll
    for (int j = 0; j < 8; ++j) {
      const f4_t av4 = half ? B[j] : A[j];
      const int g = (half * 8 + j) * 64 + lane;
      const uint4 qE = tabE[g];
      const uint4 qO = tabO[g];
      const h2_t hA = pk2(av4.x, av4.y);
      const h2_t hB = pk2(av4.z, av4.w);
      {
        const h2_t cc = bch2(qE.x), ss = bch2(qE.y), xx = bch2(qE.z), vv = bch2(qE.w);
        const h2_t tx = hA * xx;
        a0 = fdot2(hA, cc, a0);
        a1 = fdot2(hA, ss, a1);
        a2 = fdot2(tx, cc, a2);
        a3 = fdot2(tx, ss, a3);
        a4 = fdot2(hA, vv, a4);
        a5 = fdot2(hA, xx, a5);
        a6 = fdot2(hA, ONE, a6);
      }
      {
        const h2_t cc = bch2(qO.x), ss = bch2(qO.y), xx = bch2(qO.z), vv = bch2(qO.w);
        const h2_t tx = hB * xx;
        a0 = fdot2(hB, cc, a0);
        a1 = fdot2(hB, ss, a1);
        a2 = fdot2(tx, cc, a2);
        a3 = fdot2(tx, ss, a3);
        a4 = fdot2(hB, vv, a4);
        a5 = fdot2(hB, xx, a5);
        a6 = fdot2(hB, ONE, a6);
      }
    }
  }

  float S[7] = {a0, a1, a2, a3, a4, a5, a6};
#pragma unroll
  for (int j = 0; j < 7; ++j) {
    float v = S[j];
    v += __shfl_xor(v, 1);
    v += __shfl_xor(v, 2);
    v += __shfl_xor(v, 4);
    v += __shfl_xor(v, 8);
    v += __shfl_xor(v, 16);
    v += __shfl_xor(v, 32);
    S[j] = v;
  }

  float d0 = 0.f, d1 = 0.f, G0 = 0.f, G1 = 0.f;
  if (lane == 0) {
    const int i = row;
    const float x1i = x[i];
    const float x2i = x[NN + i];
    const float2 au = aux[i];
    d0 = au.x; d1 = au.y;
    G0 = G[2 * i]; G1 = G[2 * i + 1];
    const float ci = cosf(x1i), si = sinf(x1i);

    const float sint = ci * x2i * S[0] + si * x2i * S[1] - ci * S[2] - si * S[3];
    out[i] = x2i;
    out[NN + i] = (KCOUPLING / (float)NN) * (-S[4]) * sint;

    const float sw = (G0 * G0 + G1 * G1) * (1.0f / ((float)NN * (float)NN));
    gdeg[w] = sw * S[6] * S[6];
  }
  __syncthreads();
  if (lane == 0) {
    float gp = 0.0f;
#pragma unroll
    for (int r = 0; r < ROWS; ++r) gp += gdeg[r];
    const float gamma = 0.85f * gp * (1.0f / (float)ROWS);
    const int i = row;
    out[2 * NN + 2 * i + 0] = -d1 - gamma * d0 + (G0 * (1.0f / NN)) * S[5];
    out[2 * NN + 2 * i + 1] =  d0 - gamma * d1 + (G1 * (1.0f / NN)) * S[5];
  }
}

extern "C" void kernel_launch(void* const* d_in, const int* in_sizes, int n_in,
                              void* d_out, int out_size, void* d_ws,
                              size_t ws_size, hipStream_t stream) {
  (void)in_sizes; (void)n_in; (void)out_size; (void)ws_size;
  const float* x   = (const float*)d_in[1];
  const f4_t*  adj4 = (const f4_t*)d_in[2];
  const float* K   = (const float*)d_in[3];
  const float* b   = (const float*)d_in[4];
  const float* G   = (const float*)d_in[5];
  float* out = (float*)d_out;

  char* ws = (char*)d_ws;
  uint4*  wsE = (uint4*)(ws);             // 16 KB
  uint4*  wsO = (uint4*)(ws + 16384);     // 16 KB
  float2* aux = (float2*)(ws + 32768);    // 32 KB

  k_prep<<<16, 64, 0, stream>>>(x, K, b, G, wsE, wsO, aux);
  k_main<<<NBLK, 512, 0, stream>>>(x, adj4, G, wsE, wsO, aux, out);
}